// Round 9
// baseline (319.502 us; speedup 1.0000x reference)
//
#include <hip/hip_runtime.h>

typedef unsigned short u16;
typedef unsigned int u32;

#define D_DIM 128
#define CHUNK 4096    // elements scanned per scan block (256 threads x 16)
#define NSTRIPE 32    // edge stripes for hist/scatter
#define LCN 12800     // LDS counters per partition block (51.2 KB)

typedef __attribute__((ext_vector_type(8))) short bf16x8;
typedef __attribute__((ext_vector_type(4))) float f32x4;

__device__ __forceinline__ float bf2f(u16 h) {
    u32 u = ((u32)h) << 16;
    return __uint_as_float(u);
}
__device__ __forceinline__ u16 f2bf(float f) {
    u32 u = __float_as_uint(f);
    u32 r = (u >> 16) & 1u;
    u += 0x7fffu + r;                 // round-to-nearest-even
    return (u16)(u >> 16);
}
__device__ __forceinline__ float lo16(u32 u) { return bf2f((u16)(u & 0xffffu)); }
__device__ __forceinline__ float hi16(u32 u) { return bf2f((u16)(u >> 16)); }

// --- K1 (fused front): zero stats + dtype detect + fp32->bf16 feature copy
//     + W prepack. Per-block SELF-detection of dtype (same 4KB of feature,
//     L2-broadcast, identical result in every block -> no cross-block order).
__global__ void GCNLayer_76647986365164_kernel(
        int* p, int nwords, const u32* w, int* flag,
        const float* __restrict__ f, u16* __restrict__ fb,
        const void* __restrict__ W, u16* __restrict__ wpre,
        int total8, int zb) {
    const int tid = threadIdx.x;
    const int b = blockIdx.x;
    if (b < zb) {                               // zero section (stats only now)
        int i = b * 256 + tid;
        if (i < nwords) p[i] = 0;
        return;
    }
    __shared__ int cnt;
    if (tid == 0) cnt = 0;
    __syncthreads();
    {
        int c = 0;
        for (int j = 0; j < 4; ++j) {
            u32 x = w[tid * 4 + j];
            u32 e = (x >> 7) & 0xFFu;
            if (e >= 100u && e <= 140u) c++;
        }
        atomicAdd(&cnt, c);
    }
    __syncthreads();
    const int bf = (cnt >= 700) ? 1 : 0;
    if (b == zb && tid == 0) flag[0] = bf;

    if (b == gridDim.x - 1) {                   // W prepack block
        #pragma unroll
        for (int i = 0; i < 8; ++i) {
            int idx = i * 256 + tid;            // 2048 fragment units
            int frag = idx >> 6, dl = idx & 63;
            int ot = frag >> 2, kt = frag & 3;
            int dg = dl >> 4, dc = dl & 15;
            int row = ot * 16 + dc, col = kt * 32 + dg * 8;
            if (bf) {
                *(uint4*)(wpre + (size_t)idx * 8) =
                    *(const uint4*)((const u16*)W + row * 128 + col);
            } else {
                const float* Wf = (const float*)W;
                float4 x = *(const float4*)(Wf + row * 128 + col);
                float4 y = *(const float4*)(Wf + row * 128 + col + 4);
                float v[8] = {x.x, x.y, x.z, x.w, y.x, y.y, y.z, y.w};
                u16 h0[8], h1[8];
                #pragma unroll
                for (int j = 0; j < 8; ++j) {
                    h0[j] = f2bf(v[j]);
                    h1[j] = f2bf(v[j] - bf2f(h0[j]));   // residual plane
                }
                uint4 p0, p1;
                p0.x = (u32)h0[0] | ((u32)h0[1] << 16);
                p0.y = (u32)h0[2] | ((u32)h0[3] << 16);
                p0.z = (u32)h0[4] | ((u32)h0[5] << 16);
                p0.w = (u32)h0[6] | ((u32)h0[7] << 16);
                p1.x = (u32)h1[0] | ((u32)h1[1] << 16);
                p1.y = (u32)h1[2] | ((u32)h1[3] << 16);
                p1.z = (u32)h1[4] | ((u32)h1[5] << 16);
                p1.w = (u32)h1[6] | ((u32)h1[7] << 16);
                *(uint4*)(wpre + (size_t)idx * 8) = p0;
                *(uint4*)(wpre + 16384 + (size_t)idx * 8) = p1;
            }
        }
        return;
    }
    if (bf) return;                  // input already bf16, no feature copy
    int i = (b - zb) * 256 + tid;    // tobf section
    if (i >= total8) return;
    float4 a = ((const float4*)f)[i * 2];
    float4 bb = ((const float4*)f)[i * 2 + 1];
    uint4 o;
    o.x = (u32)f2bf(a.x) | ((u32)f2bf(a.y) << 16);
    o.y = (u32)f2bf(a.z) | ((u32)f2bf(a.w) << 16);
    o.z = (u32)f2bf(bb.x) | ((u32)f2bf(bb.y) << 16);
    o.w = (u32)f2bf(bb.z) | ((u32)f2bf(bb.w) << 16);
    ((uint4*)fb)[i] = o;
}

// --- K2: per-stripe per-partition histogram, ZERO global atomics ------------
// R7 post-mortem: 1M returning global atomicAdds are fabric-RMW-throughput
// bound (~40us; 4x ILP in R7 changed nothing, and device-scope RMWs cannot
// execute in the non-coherent per-XCD L2s). Replace with CU-local LDS
// counting; each block owns an exclusive cnt[stripe][node-slice] -> plain
// coalesced stores.
__global__ __launch_bounds__(256)
void k_hist(const int* __restrict__ dst, int* __restrict__ cnt,
            int E, int N, int nper, int ES, int P) {
    __shared__ int lc[LCN];
    const int tid = threadIdx.x;
    const int p = blockIdx.x % P;
    const int s = blockIdx.x / P;
    const int lo = p * nper;
    const int hi = min(lo + nper, N);
    const int cn = hi - lo;
    for (int t = tid; t < cn; t += 256) lc[t] = 0;
    __syncthreads();
    const int base = s * ES;
    const int end = min(base + ES, E);
    for (int i = base + tid * 4; i < end; i += 1024) {
        if (i + 3 < end) {
            int4 d4 = *(const int4*)(dst + i);
            if (d4.x >= lo && d4.x < hi) atomicAdd(&lc[d4.x - lo], 1);
            if (d4.y >= lo && d4.y < hi) atomicAdd(&lc[d4.y - lo], 1);
            if (d4.z >= lo && d4.z < hi) atomicAdd(&lc[d4.z - lo], 1);
            if (d4.w >= lo && d4.w < hi) atomicAdd(&lc[d4.w - lo], 1);
        } else {
            for (int k = i; k < end; ++k) {
                int d = dst[k];
                if (d >= lo && d < hi) atomicAdd(&lc[d - lo], 1);
            }
        }
    }
    __syncthreads();
    int* crow = cnt + (size_t)s * N + lo;
    for (int t = tid; t < cn; t += 256) crow[t] = lc[t];
}

// --- K2b: per-node exclusive prefix over stripes (in place) + deg -----------
// 32 independent loads -> register prefix -> 32 stores; no dependent-load
// chains (R4 lesson), no atomics.
__global__ void k_colscan(int* __restrict__ cnt, int* __restrict__ deg, int N) {
    int n = blockIdx.x * 256 + threadIdx.x;
    if (n >= N) return;
    int c[NSTRIPE];
    #pragma unroll
    for (int s = 0; s < NSTRIPE; ++s) c[s] = cnt[(size_t)s * N + n];
    int run = 0;
    #pragma unroll
    for (int s = 0; s < NSTRIPE; ++s) {
        int t = c[s];
        cnt[(size_t)s * N + n] = run;          // cnt becomes `bases`
        run += t;
    }
    deg[n] = run;
}

// --- K3a: block-local exclusive scan (multi-block; LDS Hillis-Steele) -------
__global__ void k_scan_local(const int* deg, int* offs, int* bsums, int n) {
    __shared__ int tsum[256];
    const int tid = threadIdx.x;
    const int base = blockIdx.x * CHUNK + tid * 16;
    int v[16];
    int run = 0;
    for (int j = 0; j < 16; ++j) {
        int idx = base + j;
        v[j] = (idx < n) ? deg[idx] : 0;
        run += v[j];
    }
    tsum[tid] = run;
    __syncthreads();
    for (int off = 1; off < 256; off <<= 1) {      // inclusive scan of thread sums
        int val = tsum[tid];
        int add = (tid >= off) ? tsum[tid - off] : 0;
        __syncthreads();
        tsum[tid] = val + add;
        __syncthreads();
    }
    int acc = tsum[tid] - run;                     // exclusive start (local)
    for (int j = 0; j < 16; ++j) {
        int idx = base + j;
        if (idx < n) offs[idx] = acc;
        acc += v[j];
    }
    if (tid == 255) bsums[blockIdx.x] = tsum[255];
}

// --- K3b: add scanned block totals; carry via wave-parallel reduce ----------
__global__ void k_scan_add(int* offs, const int* bsums, int n, int nblk) {
    __shared__ int carry_s;
    const int tid = threadIdx.x;
    const int b = blockIdx.x;
    if (tid < 64) {
        int acc = 0;
        for (int k = tid; k < b; k += 64) acc += bsums[k];
        #pragma unroll
        for (int off = 1; off < 64; off <<= 1) acc += __shfl_xor(acc, off);
        if (tid == 0) {
            carry_s = acc;
            if (b == nblk - 1) offs[n] = acc + bsums[b];   // total == E
        }
    }
    __syncthreads();
    const int carry = carry_s;
    const int base = b * CHUNK + tid * 16;
    for (int j = 0; j < 16; ++j) {
        int idx = base + j;
        if (idx < n) offs[idx] += carry;
    }
}

// --- K4: scatter via LDS ranks + bases, ZERO global atomics -----------------
// pos = offs[d] + bases[s][d] + lds_rank: unique by construction (bases is
// the exclusive stripe prefix of cnt). offs/bases gathers hit the block's
// partition slice (L2-hot). csr writes stay partition-local.
__global__ __launch_bounds__(256)
void k_scatter(const int* __restrict__ src, const int* __restrict__ dst,
               const int* __restrict__ bases, const int* __restrict__ offs,
               int* __restrict__ csr, int E, int N, int nper, int ES, int P) {
    __shared__ int lc[LCN];
    const int tid = threadIdx.x;
    const int p = blockIdx.x % P;
    const int s = blockIdx.x / P;
    const int lo = p * nper;
    const int hi = min(lo + nper, N);
    const int cn = hi - lo;
    for (int t = tid; t < cn; t += 256) lc[t] = 0;
    __syncthreads();
    const int base = s * ES;
    const int end = min(base + ES, E);
    const int* brow = bases + (size_t)s * N;
    for (int i = base + tid * 4; i < end; i += 1024) {
        if (i + 3 < end) {
            int4 d4 = *(const int4*)(dst + i);
            int4 s4 = *(const int4*)(src + i);
            if (d4.x >= lo && d4.x < hi) {
                int lr = atomicAdd(&lc[d4.x - lo], 1);
                csr[offs[d4.x] + brow[d4.x] + lr] = s4.x;
            }
            if (d4.y >= lo && d4.y < hi) {
                int lr = atomicAdd(&lc[d4.y - lo], 1);
                csr[offs[d4.y] + brow[d4.y] + lr] = s4.y;
            }
            if (d4.z >= lo && d4.z < hi) {
                int lr = atomicAdd(&lc[d4.z - lo], 1);
                csr[offs[d4.z] + brow[d4.z] + lr] = s4.z;
            }
            if (d4.w >= lo && d4.w < hi) {
                int lr = atomicAdd(&lc[d4.w - lo], 1);
                csr[offs[d4.w] + brow[d4.w] + lr] = s4.w;
            }
        } else {
            for (int k = i; k < end; ++k) {
                int d = dst[k];
                if (d >= lo && d < hi) {
                    int lr = atomicAdd(&lc[d - lo], 1);
                    csr[offs[d] + brow[d] + lr] = src[k];
                }
            }
        }
    }
}

// --- K5: gather-reduce mean aggregation, 16 LANES PER NODE ------------------
// ~5.7 TB/s delivered (256MB/44.6us) ~ 91% of achievable; left unchanged.
__global__ void k_aggregate(const void* feature, const u16* __restrict__ fcopy,
                            const int* offs, const int* csr, u16* agg,
                            const int* flag, int n, int npad) {
    const int tid = threadIdx.x;
    const int node = blockIdx.x * 16 + (tid >> 4);
    const int c = tid & 15;        // 16B chunk (8 bf16 cols) within row
    if (node >= npad) return;
    const u16* fb = flag[0] ? (const u16*)feature : fcopy;
    const uint4* fq = (const uint4*)fb;   // row = 16 uint4
    float acc[8];
    #pragma unroll
    for (int t = 0; t < 8; ++t) acc[t] = 0.f;
    int degn = 0;
    if (node < n) {
        int s = offs[node], e = offs[node + 1];
        degn = e - s;
        for (int j = s; j < e; j += 4) {
            int j1 = j + 1, j2 = j + 2, j3 = j + 3;
            uint4 u0 = {0,0,0,0}, u1 = {0,0,0,0}, u2 = {0,0,0,0}, u3 = {0,0,0,0};
            u0 = fq[(size_t)csr[j] * 16 + c];                  // j<e by loop cond
            if (j1 < e) u1 = fq[(size_t)csr[j1] * 16 + c];
            if (j2 < e) u2 = fq[(size_t)csr[j2] * 16 + c];
            if (j3 < e) u3 = fq[(size_t)csr[j3] * 16 + c];
            #define ACC8(U) \
                acc[0] += lo16(U.x); acc[1] += hi16(U.x); \
                acc[2] += lo16(U.y); acc[3] += hi16(U.y); \
                acc[4] += lo16(U.z); acc[5] += hi16(U.z); \
                acc[6] += lo16(U.w); acc[7] += hi16(U.w);
            ACC8(u0); ACC8(u1); ACC8(u2); ACC8(u3);
            #undef ACC8
        }
    }
    float sc = 1.0f / (float)(degn > 1 ? degn : 1);
    uint4 o4;
    o4.x = (u32)f2bf(acc[0] * sc) | ((u32)f2bf(acc[1] * sc) << 16);
    o4.y = (u32)f2bf(acc[2] * sc) | ((u32)f2bf(acc[3] * sc) << 16);
    o4.z = (u32)f2bf(acc[4] * sc) | ((u32)f2bf(acc[5] * sc) << 16);
    o4.w = (u32)f2bf(acc[6] * sc) | ((u32)f2bf(acc[7] * sc) << 16);
    ((uint4*)(agg + (size_t)node * D_DIM))[c] = o4;
}

// --- K6: h = agg @ W^T + b via bf16 MFMA, prepacked W, h in place -----------
__global__ __launch_bounds__(512, 4)
void k_gemm(u16* __restrict__ agg, const u16* __restrict__ wpre,
            const void* __restrict__ bias, float* __restrict__ parts,
            const int* __restrict__ flag, int n) {
    __shared__ u16 sW[2048 * 8];              // 32 KB: one plane
    const int tid = threadIdx.x;
    const int rb = blockIdx.x * 128;
    const int bf = flag[0];
    const int w = tid >> 6;
    const int lane = tid & 63;
    const int g = lane >> 4, c = lane & 15;

    // A fragments first (independent global loads, overlap the stage)
    bf16x8 afr[4];
    {
        const u16* arow = agg + (size_t)(rb + w * 16 + c) * D_DIM + g * 8;
        #pragma unroll
        for (int kt = 0; kt < 4; ++kt)
            afr[kt] = *(const bf16x8*)(arow + kt * 32);
    }

    f32x4 acc[8];
    #pragma unroll
    for (int ot = 0; ot < 8; ++ot) acc[ot] = (f32x4){0.f, 0.f, 0.f, 0.f};

    const int npass = bf ? 1 : 2;
    for (int pass = 0; pass < npass; ++pass) {
        if (pass) __syncthreads();             // all waves done reading plane0
        const u16* wsrc = wpre + (size_t)pass * 16384;
        #pragma unroll
        for (int i = 0; i < 4; ++i) {          // pure coalesced uint4 copy
            int idx = i * 512 + tid;
            *(uint4*)(&sW[idx * 8]) = *(const uint4*)(wsrc + (size_t)idx * 8);
        }
        __syncthreads();
        #pragma unroll
        for (int ot = 0; ot < 8; ++ot) {
            #pragma unroll
            for (int kt = 0; kt < 4; ++kt) {
                bf16x8 bfr = *(const bf16x8*)(&sW[((ot * 4 + kt) * 64 + lane) * 8]);
                acc[ot] = __builtin_amdgcn_mfma_f32_16x16x32_bf16(
                    afr[kt], bfr, acc[ot], 0, 0, 0);
            }
        }
    }

    // sW is dead from here on: reuse as float scratch for BN partials
    float* red = (float*)sW;                   // [8][256] floats = 8 KB
    __syncthreads();                           // all waves done reading sW

    const int rowbase = rb + w * 16 + g * 4;
    #pragma unroll
    for (int ot = 0; ot < 8; ++ot) {
        const int o = ot * 16 + c;
        float bv = bf ? bf2f(((const u16*)bias)[o]) : ((const float*)bias)[o];
        float s = 0.f, q = 0.f;
        float hv[4];
        #pragma unroll
        for (int r = 0; r < 4; ++r) {
            float h = acc[ot][r] + bv;
            hv[r] = h;
            if (rowbase + r < n) { s += h; q += h * h; }
        }
        #pragma unroll
        for (int r = 0; r < 4; ++r) {
            float hp = __shfl_xor(hv[r], 1);       // neighbor col (o^1)
            if (!(lane & 1)) {
                u32 pk = (u32)f2bf(hv[r]) | ((u32)f2bf(hp) << 16);
                *(u32*)(agg + (size_t)(rowbase + r) * D_DIM + o) = pk;
            }
        }
        s += __shfl_xor(s, 16); s += __shfl_xor(s, 32);
        q += __shfl_xor(q, 16); q += __shfl_xor(q, 32);
        if (g == 0) { red[w * 256 + o] = s; red[w * 256 + 128 + o] = q; }
    }
    __syncthreads();
    if (tid < 256) {                            // cross-wave reduce, one row/block
        float a = 0.f;
        #pragma unroll
        for (int ww = 0; ww < 8; ++ww) a += red[ww * 256 + tid];
        parts[(size_t)blockIdx.x * 256 + tid] = a;
    }
}

// --- K6b: reduce per-block BN partials into stats ---------------------------
__global__ void k_redstats(const float* __restrict__ partials,
                           float* __restrict__ stats, int nb) {
    const int tid = threadIdx.x;
    float a0 = 0.f, a1 = 0.f, a2 = 0.f, a3 = 0.f;
    float a4 = 0.f, a5 = 0.f, a6 = 0.f, a7 = 0.f;
    for (int r0 = blockIdx.x * 8; r0 < nb; r0 += gridDim.x * 8) {
        if (r0 + 0 < nb) a0 += partials[(size_t)(r0 + 0) * 256 + tid];
        if (r0 + 1 < nb) a1 += partials[(size_t)(r0 + 1) * 256 + tid];
        if (r0 + 2 < nb) a2 += partials[(size_t)(r0 + 2) * 256 + tid];
        if (r0 + 3 < nb) a3 += partials[(size_t)(r0 + 3) * 256 + tid];
        if (r0 + 4 < nb) a4 += partials[(size_t)(r0 + 4) * 256 + tid];
        if (r0 + 5 < nb) a5 += partials[(size_t)(r0 + 5) * 256 + tid];
        if (r0 + 6 < nb) a6 += partials[(size_t)(r0 + 6) * 256 + tid];
        if (r0 + 7 < nb) a7 += partials[(size_t)(r0 + 7) * 256 + tid];
    }
    float s = ((a0 + a1) + (a2 + a3)) + ((a4 + a5) + (a6 + a7));
    atomicAdd(&stats[tid], s);
}

// --- K8: out = feature + relu(h*scale + shift); BN finalize folded in -------
__global__ void k_apply(const u16* h, const void* feature, const float* stats,
                        const void* gamma, const void* beta, void* outp,
                        const int* flag, int total8, float invn) {
    __shared__ float ssc[128], ssh[128];
    int tid = threadIdx.x;
    int bf = flag[0];
    if (tid < 128) {
        float mean = stats[tid] * invn;
        float var = stats[128 + tid] * invn - mean * mean;
        var = fmaxf(var, 0.f);
        float inv = rsqrtf(var + 1e-5f);
        float g = bf ? bf2f(((const u16*)gamma)[tid]) : ((const float*)gamma)[tid];
        float bb = bf ? bf2f(((const u16*)beta)[tid]) : ((const float*)beta)[tid];
        float sc = inv * g;
        ssc[tid] = sc;
        ssh[tid] = bb - mean * sc;
    }
    __syncthreads();
    int i = blockIdx.x * 256 + tid;
    if (i >= total8) return;
    size_t base = (size_t)i * 8;
    int c0 = (int)(base & (D_DIM - 1));
    uint4 h4 = ((const uint4*)h)[i];
    u32 hw[4] = {h4.x, h4.y, h4.z, h4.w};
    float hv[8];
    for (int j = 0; j < 4; ++j) { hv[2*j] = lo16(hw[j]); hv[2*j+1] = hi16(hw[j]); }
    float fv[8];
    if (bf) {
        uint4 f4 = ((const uint4*)feature)[i];
        u32 fw[4] = {f4.x, f4.y, f4.z, f4.w};
        for (int j = 0; j < 4; ++j) { fv[2*j] = lo16(fw[j]); fv[2*j+1] = hi16(fw[j]); }
    } else {
        float4 fa = ((const float4*)feature)[i * 2];
        float4 fb = ((const float4*)feature)[i * 2 + 1];
        fv[0]=fa.x; fv[1]=fa.y; fv[2]=fa.z; fv[3]=fa.w;
        fv[4]=fb.x; fv[5]=fb.y; fv[6]=fb.z; fv[7]=fb.w;
    }
    float ov[8];
    for (int j = 0; j < 8; ++j)
        ov[j] = fmaxf(hv[j] * ssc[c0 + j] + ssh[c0 + j], 0.f) + fv[j];
    if (bf) {
        uint4 o4;
        u32 ow[4];
        for (int j = 0; j < 4; ++j)
            ow[j] = (u32)f2bf(ov[2*j]) | ((u32)f2bf(ov[2*j+1]) << 16);
        o4.x = ow[0]; o4.y = ow[1]; o4.z = ow[2]; o4.w = ow[3];
        ((uint4*)outp)[i] = o4;
    } else {
        float4 oa, ob;
        oa.x=ov[0]; oa.y=ov[1]; oa.z=ov[2]; oa.w=ov[3];
        ob.x=ov[4]; ob.y=ov[5]; ob.z=ov[6]; ob.w=ov[7];
        ((float4*)outp)[i * 2] = oa;
        ((float4*)outp)[i * 2 + 1] = ob;
    }
}

static inline size_t al256s(size_t x) { return (x + 255) & ~(size_t)255; }
static inline int gmax1(int x) { return x > 0 ? x : 1; }

extern "C" void kernel_launch(void* const* d_in, const int* in_sizes, int n_in,
                              void* d_out, int out_size, void* d_ws, size_t ws_size,
                              hipStream_t stream) {
    const void* feature = d_in[0];
    const int*  src     = (const int*)d_in[1];
    const int*  dst     = (const int*)d_in[2];
    const void* W       = d_in[3];
    const void* bias    = d_in[4];
    const void* gamma   = d_in[5];
    const void* beta    = d_in[6];

    const int N = in_sizes[0] / D_DIM;
    const int E = in_sizes[1];
    const int Npad = (N + 127) & ~127;             // 128-row gemm blocks
    const int nblk = (N + CHUNK - 1) / CHUNK;      // scan blocks
    const int gb   = Npad / 128;                   // gemm blocks == partial rows

    // hist/scatter geometry: P partitions sized to fit LDS counters
    int P = (N + LCN - 1) / LCN;  if (P < 8) P = 8;
    const int nper = (N + P - 1) / P;
    const int ES = (((E + NSTRIPE - 1) / NSTRIPE) + 3) & ~3;   // 16B-aligned stripes

    char* p = (char*)d_ws;
    size_t o = 0;
    int*   flag   = (int*)(p + o);      o += 256;
    int*   deg    = (int*)(p + o);      o += al256s((size_t)N * 4);
    float* stats  = (float*)(p + o);    o += 256 * 4;           // sum[128],sq[128]
    o = al256s(o);
    u16*   wpre   = (u16*)(p + o);      o += al256s(2 * 16384 * 2);  // 2 bf16 planes
    int*   bsums  = (int*)(p + o);      o += al256s(((size_t)nblk + 8) * 4);
    int*   offs   = (int*)(p + o);      o += al256s(((size_t)N + 8) * 4);
    int*   csr    = (int*)(p + o);      o += al256s((size_t)E * 4);
    float* parts  = (float*)(p + o);    o += al256s((size_t)gb * 256 * 4);
    u16*   agg    = (u16*)(p + o);      o += al256s((size_t)Npad * D_DIM * 2);
    int*   cnt    = (int*)agg;   // aliased: cnt/bases (NSTRIPE*N ints = 12.8MB)
                                 // dies before k_aggregate writes agg (25.6MB)
    u16*   fbf    = (u16*)d_out; // bf16 feature copy; dead before k_apply writes
    (void)ws_size; (void)n_in; (void)out_size;

    int total8 = N * D_DIM / 8;
    int zb = 1;                                    // stats zero fits one block
    int tb = gmax1((total8 + 255) / 256);
    int hblocks = NSTRIPE * P;

    GCNLayer_76647986365164_kernel<<<zb + tb + 1, 256, 0, stream>>>(
        (int*)stats, 256, (const u32*)feature, flag,
        (const float*)feature, fbf, W, wpre, total8, zb);
    k_hist<<<hblocks, 256, 0, stream>>>(dst, cnt, E, N, nper, ES, P);
    k_colscan<<<gmax1((N + 255) / 256), 256, 0, stream>>>(cnt, deg, N);
    k_scan_local<<<gmax1(nblk), 256, 0, stream>>>(deg, offs, bsums, N);
    k_scan_add<<<gmax1(nblk), 256, 0, stream>>>(offs, bsums, N, nblk);
    k_scatter<<<hblocks, 256, 0, stream>>>(src, dst, cnt, offs, csr,
                                           E, N, nper, ES, P);
    k_aggregate<<<gmax1(Npad / 16), 256, 0, stream>>>(
        feature, fbf, offs, csr, agg, flag, N, Npad);
    k_gemm<<<gmax1(gb), 512, 0, stream>>>(agg, wpre, bias, parts, flag, N);
    k_redstats<<<32, 256, 0, stream>>>(parts, stats, gb);
    k_apply<<<gmax1((total8 + 255) / 256), 256, 0, stream>>>(
        agg, feature, stats, gamma, beta, d_out, flag, total8, 1.0f / (float)N);
}

// Round 10
// 281.199 us; speedup vs baseline: 1.1362x; 1.1362x over previous
//
#include <hip/hip_runtime.h>

typedef unsigned short u16;
typedef unsigned int u32;

#define D_DIM 128
#define CHUNK 4096    // elements scanned per scan block (256 threads x 16)
#define NSTRIPE 64    // edge stripes for hist/scatter (cnt = 64*N*4B fits agg)
#define LCN 12800     // LDS counters per partition block (51.2 KB)

typedef __attribute__((ext_vector_type(8))) short bf16x8;
typedef __attribute__((ext_vector_type(4))) float f32x4;

__device__ __forceinline__ float bf2f(u16 h) {
    u32 u = ((u32)h) << 16;
    return __uint_as_float(u);
}
__device__ __forceinline__ u16 f2bf(float f) {
    u32 u = __float_as_uint(f);
    u32 r = (u >> 16) & 1u;
    u += 0x7fffu + r;                 // round-to-nearest-even
    return (u16)(u >> 16);
}
__device__ __forceinline__ float lo16(u32 u) { return bf2f((u16)(u & 0xffffu)); }
__device__ __forceinline__ float hi16(u32 u) { return bf2f((u16)(u >> 16)); }

// --- K1 (fused front): zero stats + dtype detect + fp32->bf16 feature copy
//     + W prepack. Per-block SELF-detection of dtype (same 4KB of feature,
//     L2-broadcast, identical result in every block -> no cross-block order).
__global__ void GCNLayer_76647986365164_kernel(
        int* p, int nwords, const u32* w, int* flag,
        const float* __restrict__ f, u16* __restrict__ fb,
        const void* __restrict__ W, u16* __restrict__ wpre,
        int total8, int zb) {
    const int tid = threadIdx.x;
    const int b = blockIdx.x;
    if (b < zb) {                               // zero section (stats only now)
        int i = b * 256 + tid;
        if (i < nwords) p[i] = 0;
        return;
    }
    __shared__ int cnt;
    if (tid == 0) cnt = 0;
    __syncthreads();
    {
        int c = 0;
        for (int j = 0; j < 4; ++j) {
            u32 x = w[tid * 4 + j];
            u32 e = (x >> 7) & 0xFFu;
            if (e >= 100u && e <= 140u) c++;
        }
        atomicAdd(&cnt, c);
    }
    __syncthreads();
    const int bf = (cnt >= 700) ? 1 : 0;
    if (b == zb && tid == 0) flag[0] = bf;

    if (b == gridDim.x - 1) {                   // W prepack block
        #pragma unroll
        for (int i = 0; i < 8; ++i) {
            int idx = i * 256 + tid;            // 2048 fragment units
            int frag = idx >> 6, dl = idx & 63;
            int ot = frag >> 2, kt = frag & 3;
            int dg = dl >> 4, dc = dl & 15;
            int row = ot * 16 + dc, col = kt * 32 + dg * 8;
            if (bf) {
                *(uint4*)(wpre + (size_t)idx * 8) =
                    *(const uint4*)((const u16*)W + row * 128 + col);
            } else {
                const float* Wf = (const float*)W;
                float4 x = *(const float4*)(Wf + row * 128 + col);
                float4 y = *(const float4*)(Wf + row * 128 + col + 4);
                float v[8] = {x.x, x.y, x.z, x.w, y.x, y.y, y.z, y.w};
                u16 h0[8], h1[8];
                #pragma unroll
                for (int j = 0; j < 8; ++j) {
                    h0[j] = f2bf(v[j]);
                    h1[j] = f2bf(v[j] - bf2f(h0[j]));   // residual plane
                }
                uint4 p0, p1;
                p0.x = (u32)h0[0] | ((u32)h0[1] << 16);
                p0.y = (u32)h0[2] | ((u32)h0[3] << 16);
                p0.z = (u32)h0[4] | ((u32)h0[5] << 16);
                p0.w = (u32)h0[6] | ((u32)h0[7] << 16);
                p1.x = (u32)h1[0] | ((u32)h1[1] << 16);
                p1.y = (u32)h1[2] | ((u32)h1[3] << 16);
                p1.z = (u32)h1[4] | ((u32)h1[5] << 16);
                p1.w = (u32)h1[6] | ((u32)h1[7] << 16);
                *(uint4*)(wpre + (size_t)idx * 8) = p0;
                *(uint4*)(wpre + 16384 + (size_t)idx * 8) = p1;
            }
        }
        return;
    }
    if (bf) return;                  // input already bf16, no feature copy
    int i = (b - zb) * 256 + tid;    // tobf section
    if (i >= total8) return;
    float4 a = ((const float4*)f)[i * 2];
    float4 bb = ((const float4*)f)[i * 2 + 1];
    uint4 o;
    o.x = (u32)f2bf(a.x) | ((u32)f2bf(a.y) << 16);
    o.y = (u32)f2bf(a.z) | ((u32)f2bf(a.w) << 16);
    o.z = (u32)f2bf(bb.x) | ((u32)f2bf(bb.y) << 16);
    o.w = (u32)f2bf(bb.z) | ((u32)f2bf(bb.w) << 16);
    ((uint4*)fb)[i] = o;
}

// --- K2: per-stripe per-partition histogram, ZERO global atomics ------------
// LDS counting (CU-local, ~100x fabric RMW throughput); each block owns an
// exclusive cnt[stripe][node-slice] -> plain coalesced stores.
// R10: NSTRIPE 32 -> 64 (grid 256 -> 512 = 2 blocks/CU; R9 had 1/CU).
__global__ __launch_bounds__(256)
void k_hist(const int* __restrict__ dst, int* __restrict__ cnt,
            int E, int N, int nper, int ES, int P) {
    __shared__ int lc[LCN];
    const int tid = threadIdx.x;
    const int p = blockIdx.x % P;
    const int s = blockIdx.x / P;
    const int lo = p * nper;
    const int hi = min(lo + nper, N);
    const int cn = hi - lo;
    for (int t = tid; t < cn; t += 256) lc[t] = 0;
    __syncthreads();
    const int base = s * ES;
    const int end = min(base + ES, E);
    for (int i = base + tid * 4; i < end; i += 1024) {
        if (i + 3 < end) {
            int4 d4 = *(const int4*)(dst + i);
            if (d4.x >= lo && d4.x < hi) atomicAdd(&lc[d4.x - lo], 1);
            if (d4.y >= lo && d4.y < hi) atomicAdd(&lc[d4.y - lo], 1);
            if (d4.z >= lo && d4.z < hi) atomicAdd(&lc[d4.z - lo], 1);
            if (d4.w >= lo && d4.w < hi) atomicAdd(&lc[d4.w - lo], 1);
        } else {
            for (int k = i; k < end; ++k) {
                int d = dst[k];
                if (d >= lo && d < hi) atomicAdd(&lc[d - lo], 1);
            }
        }
    }
    __syncthreads();
    int* crow = cnt + (size_t)s * N + lo;
    for (int t = tid; t < cn; t += 256) crow[t] = lc[t];
}

// --- K2b: per-node exclusive prefix over stripes (in place) + deg -----------
// Inline load/store/add loop (no 64-register array); compiler pipelines the
// independent strided loads.
__global__ void k_colscan(int* __restrict__ cnt, int* __restrict__ deg, int N) {
    int n = blockIdx.x * 256 + threadIdx.x;
    if (n >= N) return;
    int run = 0;
    #pragma unroll
    for (int s = 0; s < NSTRIPE; ++s) {
        int t = cnt[(size_t)s * N + n];
        cnt[(size_t)s * N + n] = run;          // cnt becomes `bases`
        run += t;
    }
    deg[n] = run;
}

// --- K3a: block-local exclusive scan (multi-block; LDS Hillis-Steele) -------
__global__ void k_scan_local(const int* deg, int* offs, int* bsums, int n) {
    __shared__ int tsum[256];
    const int tid = threadIdx.x;
    const int base = blockIdx.x * CHUNK + tid * 16;
    int v[16];
    int run = 0;
    for (int j = 0; j < 16; ++j) {
        int idx = base + j;
        v[j] = (idx < n) ? deg[idx] : 0;
        run += v[j];
    }
    tsum[tid] = run;
    __syncthreads();
    for (int off = 1; off < 256; off <<= 1) {      // inclusive scan of thread sums
        int val = tsum[tid];
        int add = (tid >= off) ? tsum[tid - off] : 0;
        __syncthreads();
        tsum[tid] = val + add;
        __syncthreads();
    }
    int acc = tsum[tid] - run;                     // exclusive start (local)
    for (int j = 0; j < 16; ++j) {
        int idx = base + j;
        if (idx < n) offs[idx] = acc;
        acc += v[j];
    }
    if (tid == 255) bsums[blockIdx.x] = tsum[255];
}

// --- K3b: add scanned block totals; carry via wave-parallel reduce ----------
__global__ void k_scan_add(int* offs, const int* bsums, int n, int nblk) {
    __shared__ int carry_s;
    const int tid = threadIdx.x;
    const int b = blockIdx.x;
    if (tid < 64) {
        int acc = 0;
        for (int k = tid; k < b; k += 64) acc += bsums[k];
        #pragma unroll
        for (int off = 1; off < 64; off <<= 1) acc += __shfl_xor(acc, off);
        if (tid == 0) {
            carry_s = acc;
            if (b == nblk - 1) offs[n] = acc + bsums[b];   // total == E
        }
    }
    __syncthreads();
    const int carry = carry_s;
    const int base = b * CHUNK + tid * 16;
    for (int j = 0; j < 16; ++j) {
        int idx = base + j;
        if (idx < n) offs[idx] += carry;
    }
}

// --- K4: scatter, counters PRE-INITIALIZED with absolute csr positions ------
// R9 post-mortem: 64.6us at 9.7% occupancy -- per-edge random gathers of
// offs[d]+bases[s][d] (2M scattered loads) behind a 256-block grid.
// R10 fix: lc[t] = offs[lo+t] + bases[s][lo+t] at init (coalesced slice
// reads), so atomicAdd(&lc[d-lo],1) RETURNS the absolute position. Edge loop
// = coalesced int4 read -> LDS atomic -> partition-local csr write; zero
// random reads. Disjoint/covering ranges unchanged (bases = exclusive stripe
// prefix). Grid 512 = 2 blocks/CU.
__global__ __launch_bounds__(256)
void k_scatter(const int* __restrict__ src, const int* __restrict__ dst,
               const int* __restrict__ bases, const int* __restrict__ offs,
               int* __restrict__ csr, int E, int N, int nper, int ES, int P) {
    __shared__ int lc[LCN];
    const int tid = threadIdx.x;
    const int p = blockIdx.x % P;
    const int s = blockIdx.x / P;
    const int lo = p * nper;
    const int hi = min(lo + nper, N);
    const int cn = hi - lo;
    const int* brow = bases + (size_t)s * N;
    for (int t = tid; t < cn; t += 256)
        lc[t] = offs[lo + t] + brow[lo + t];
    __syncthreads();
    const int base = s * ES;
    const int end = min(base + ES, E);
    for (int i = base + tid * 4; i < end; i += 1024) {
        if (i + 3 < end) {
            int4 d4 = *(const int4*)(dst + i);
            int4 s4 = *(const int4*)(src + i);
            if (d4.x >= lo && d4.x < hi) csr[atomicAdd(&lc[d4.x - lo], 1)] = s4.x;
            if (d4.y >= lo && d4.y < hi) csr[atomicAdd(&lc[d4.y - lo], 1)] = s4.y;
            if (d4.z >= lo && d4.z < hi) csr[atomicAdd(&lc[d4.z - lo], 1)] = s4.z;
            if (d4.w >= lo && d4.w < hi) csr[atomicAdd(&lc[d4.w - lo], 1)] = s4.w;
        } else {
            for (int k = i; k < end; ++k) {
                int d = dst[k];
                if (d >= lo && d < hi) csr[atomicAdd(&lc[d - lo], 1)] = src[k];
            }
        }
    }
}

// --- K5: gather-reduce mean aggregation, 16 LANES PER NODE ------------------
// ~5.7 TB/s delivered (256MB/44.6us) ~ 91% of achievable; left unchanged.
__global__ void k_aggregate(const void* feature, const u16* __restrict__ fcopy,
                            const int* offs, const int* csr, u16* agg,
                            const int* flag, int n, int npad) {
    const int tid = threadIdx.x;
    const int node = blockIdx.x * 16 + (tid >> 4);
    const int c = tid & 15;        // 16B chunk (8 bf16 cols) within row
    if (node >= npad) return;
    const u16* fb = flag[0] ? (const u16*)feature : fcopy;
    const uint4* fq = (const uint4*)fb;   // row = 16 uint4
    float acc[8];
    #pragma unroll
    for (int t = 0; t < 8; ++t) acc[t] = 0.f;
    int degn = 0;
    if (node < n) {
        int s = offs[node], e = offs[node + 1];
        degn = e - s;
        for (int j = s; j < e; j += 4) {
            int j1 = j + 1, j2 = j + 2, j3 = j + 3;
            uint4 u0 = {0,0,0,0}, u1 = {0,0,0,0}, u2 = {0,0,0,0}, u3 = {0,0,0,0};
            u0 = fq[(size_t)csr[j] * 16 + c];                  // j<e by loop cond
            if (j1 < e) u1 = fq[(size_t)csr[j1] * 16 + c];
            if (j2 < e) u2 = fq[(size_t)csr[j2] * 16 + c];
            if (j3 < e) u3 = fq[(size_t)csr[j3] * 16 + c];
            #define ACC8(U) \
                acc[0] += lo16(U.x); acc[1] += hi16(U.x); \
                acc[2] += lo16(U.y); acc[3] += hi16(U.y); \
                acc[4] += lo16(U.z); acc[5] += hi16(U.z); \
                acc[6] += lo16(U.w); acc[7] += hi16(U.w);
            ACC8(u0); ACC8(u1); ACC8(u2); ACC8(u3);
            #undef ACC8
        }
    }
    float sc = 1.0f / (float)(degn > 1 ? degn : 1);
    uint4 o4;
    o4.x = (u32)f2bf(acc[0] * sc) | ((u32)f2bf(acc[1] * sc) << 16);
    o4.y = (u32)f2bf(acc[2] * sc) | ((u32)f2bf(acc[3] * sc) << 16);
    o4.z = (u32)f2bf(acc[4] * sc) | ((u32)f2bf(acc[5] * sc) << 16);
    o4.w = (u32)f2bf(acc[6] * sc) | ((u32)f2bf(acc[7] * sc) << 16);
    ((uint4*)(agg + (size_t)node * D_DIM))[c] = o4;
}

// --- K6: h = agg @ W^T + b via bf16 MFMA, prepacked W, h in place -----------
__global__ __launch_bounds__(512, 4)
void k_gemm(u16* __restrict__ agg, const u16* __restrict__ wpre,
            const void* __restrict__ bias, float* __restrict__ parts,
            const int* __restrict__ flag, int n) {
    __shared__ u16 sW[2048 * 8];              // 32 KB: one plane
    const int tid = threadIdx.x;
    const int rb = blockIdx.x * 128;
    const int bf = flag[0];
    const int w = tid >> 6;
    const int lane = tid & 63;
    const int g = lane >> 4, c = lane & 15;

    // A fragments first (independent global loads, overlap the stage)
    bf16x8 afr[4];
    {
        const u16* arow = agg + (size_t)(rb + w * 16 + c) * D_DIM + g * 8;
        #pragma unroll
        for (int kt = 0; kt < 4; ++kt)
            afr[kt] = *(const bf16x8*)(arow + kt * 32);
    }

    f32x4 acc[8];
    #pragma unroll
    for (int ot = 0; ot < 8; ++ot) acc[ot] = (f32x4){0.f, 0.f, 0.f, 0.f};

    const int npass = bf ? 1 : 2;
    for (int pass = 0; pass < npass; ++pass) {
        if (pass) __syncthreads();             // all waves done reading plane0
        const u16* wsrc = wpre + (size_t)pass * 16384;
        #pragma unroll
        for (int i = 0; i < 4; ++i) {          // pure coalesced uint4 copy
            int idx = i * 512 + tid;
            *(uint4*)(&sW[idx * 8]) = *(const uint4*)(wsrc + (size_t)idx * 8);
        }
        __syncthreads();
        #pragma unroll
        for (int ot = 0; ot < 8; ++ot) {
            #pragma unroll
            for (int kt = 0; kt < 4; ++kt) {
                bf16x8 bfr = *(const bf16x8*)(&sW[((ot * 4 + kt) * 64 + lane) * 8]);
                acc[ot] = __builtin_amdgcn_mfma_f32_16x16x32_bf16(
                    afr[kt], bfr, acc[ot], 0, 0, 0);
            }
        }
    }

    // sW is dead from here on: reuse as float scratch for BN partials
    float* red = (float*)sW;                   // [8][256] floats = 8 KB
    __syncthreads();                           // all waves done reading sW

    const int rowbase = rb + w * 16 + g * 4;
    #pragma unroll
    for (int ot = 0; ot < 8; ++ot) {
        const int o = ot * 16 + c;
        float bv = bf ? bf2f(((const u16*)bias)[o]) : ((const float*)bias)[o];
        float s = 0.f, q = 0.f;
        float hv[4];
        #pragma unroll
        for (int r = 0; r < 4; ++r) {
            float h = acc[ot][r] + bv;
            hv[r] = h;
            if (rowbase + r < n) { s += h; q += h * h; }
        }
        #pragma unroll
        for (int r = 0; r < 4; ++r) {
            float hp = __shfl_xor(hv[r], 1);       // neighbor col (o^1)
            if (!(lane & 1)) {
                u32 pk = (u32)f2bf(hv[r]) | ((u32)f2bf(hp) << 16);
                *(u32*)(agg + (size_t)(rowbase + r) * D_DIM + o) = pk;
            }
        }
        s += __shfl_xor(s, 16); s += __shfl_xor(s, 32);
        q += __shfl_xor(q, 16); q += __shfl_xor(q, 32);
        if (g == 0) { red[w * 256 + o] = s; red[w * 256 + 128 + o] = q; }
    }
    __syncthreads();
    if (tid < 256) {                            // cross-wave reduce, one row/block
        float a = 0.f;
        #pragma unroll
        for (int ww = 0; ww < 8; ++ww) a += red[ww * 256 + tid];
        parts[(size_t)blockIdx.x * 256 + tid] = a;
    }
}

// --- K6b: reduce per-block BN partials into stats ---------------------------
__global__ void k_redstats(const float* __restrict__ partials,
                           float* __restrict__ stats, int nb) {
    const int tid = threadIdx.x;
    float a0 = 0.f, a1 = 0.f, a2 = 0.f, a3 = 0.f;
    float a4 = 0.f, a5 = 0.f, a6 = 0.f, a7 = 0.f;
    for (int r0 = blockIdx.x * 8; r0 < nb; r0 += gridDim.x * 8) {
        if (r0 + 0 < nb) a0 += partials[(size_t)(r0 + 0) * 256 + tid];
        if (r0 + 1 < nb) a1 += partials[(size_t)(r0 + 1) * 256 + tid];
        if (r0 + 2 < nb) a2 += partials[(size_t)(r0 + 2) * 256 + tid];
        if (r0 + 3 < nb) a3 += partials[(size_t)(r0 + 3) * 256 + tid];
        if (r0 + 4 < nb) a4 += partials[(size_t)(r0 + 4) * 256 + tid];
        if (r0 + 5 < nb) a5 += partials[(size_t)(r0 + 5) * 256 + tid];
        if (r0 + 6 < nb) a6 += partials[(size_t)(r0 + 6) * 256 + tid];
        if (r0 + 7 < nb) a7 += partials[(size_t)(r0 + 7) * 256 + tid];
    }
    float s = ((a0 + a1) + (a2 + a3)) + ((a4 + a5) + (a6 + a7));
    atomicAdd(&stats[tid], s);
}

// --- K8: out = feature + relu(h*scale + shift); BN finalize folded in -------
__global__ void k_apply(const u16* h, const void* feature, const float* stats,
                        const void* gamma, const void* beta, void* outp,
                        const int* flag, int total8, float invn) {
    __shared__ float ssc[128], ssh[128];
    int tid = threadIdx.x;
    int bf = flag[0];
    if (tid < 128) {
        float mean = stats[tid] * invn;
        float var = stats[128 + tid] * invn - mean * mean;
        var = fmaxf(var, 0.f);
        float inv = rsqrtf(var + 1e-5f);
        float g = bf ? bf2f(((const u16*)gamma)[tid]) : ((const float*)gamma)[tid];
        float bb = bf ? bf2f(((const u16*)beta)[tid]) : ((const float*)beta)[tid];
        float sc = inv * g;
        ssc[tid] = sc;
        ssh[tid] = bb - mean * sc;
    }
    __syncthreads();
    int i = blockIdx.x * 256 + tid;
    if (i >= total8) return;
    size_t base = (size_t)i * 8;
    int c0 = (int)(base & (D_DIM - 1));
    uint4 h4 = ((const uint4*)h)[i];
    u32 hw[4] = {h4.x, h4.y, h4.z, h4.w};
    float hv[8];
    for (int j = 0; j < 4; ++j) { hv[2*j] = lo16(hw[j]); hv[2*j+1] = hi16(hw[j]); }
    float fv[8];
    if (bf) {
        uint4 f4 = ((const uint4*)feature)[i];
        u32 fw[4] = {f4.x, f4.y, f4.z, f4.w};
        for (int j = 0; j < 4; ++j) { fv[2*j] = lo16(fw[j]); fv[2*j+1] = hi16(fw[j]); }
    } else {
        float4 fa = ((const float4*)feature)[i * 2];
        float4 fb = ((const float4*)feature)[i * 2 + 1];
        fv[0]=fa.x; fv[1]=fa.y; fv[2]=fa.z; fv[3]=fa.w;
        fv[4]=fb.x; fv[5]=fb.y; fv[6]=fb.z; fv[7]=fb.w;
    }
    float ov[8];
    for (int j = 0; j < 8; ++j)
        ov[j] = fmaxf(hv[j] * ssc[c0 + j] + ssh[c0 + j], 0.f) + fv[j];
    if (bf) {
        uint4 o4;
        u32 ow[4];
        for (int j = 0; j < 4; ++j)
            ow[j] = (u32)f2bf(ov[2*j]) | ((u32)f2bf(ov[2*j+1]) << 16);
        o4.x = ow[0]; o4.y = ow[1]; o4.z = ow[2]; o4.w = ow[3];
        ((uint4*)outp)[i] = o4;
    } else {
        float4 oa, ob;
        oa.x=ov[0]; oa.y=ov[1]; oa.z=ov[2]; oa.w=ov[3];
        ob.x=ov[4]; ob.y=ov[5]; ob.z=ov[6]; ob.w=ov[7];
        ((float4*)outp)[i * 2] = oa;
        ((float4*)outp)[i * 2 + 1] = ob;
    }
}

static inline size_t al256s(size_t x) { return (x + 255) & ~(size_t)255; }
static inline int gmax1(int x) { return x > 0 ? x : 1; }
static inline size_t smax(size_t a, size_t b) { return a > b ? a : b; }

extern "C" void kernel_launch(void* const* d_in, const int* in_sizes, int n_in,
                              void* d_out, int out_size, void* d_ws, size_t ws_size,
                              hipStream_t stream) {
    const void* feature = d_in[0];
    const int*  src     = (const int*)d_in[1];
    const int*  dst     = (const int*)d_in[2];
    const void* W       = d_in[3];
    const void* bias    = d_in[4];
    const void* gamma   = d_in[5];
    const void* beta    = d_in[6];

    const int N = in_sizes[0] / D_DIM;
    const int E = in_sizes[1];
    const int Npad = (N + 127) & ~127;             // 128-row gemm blocks
    const int nblk = (N + CHUNK - 1) / CHUNK;      // scan blocks
    const int gb   = Npad / 128;                   // gemm blocks == partial rows

    // hist/scatter geometry: P partitions sized to fit LDS counters
    int P = (N + LCN - 1) / LCN;  if (P < 8) P = 8;
    const int nper = (N + P - 1) / P;
    const int ES = (((E + NSTRIPE - 1) / NSTRIPE) + 3) & ~3;   // 16B-aligned stripes

    char* p = (char*)d_ws;
    size_t o = 0;
    int*   flag   = (int*)(p + o);      o += 256;
    int*   deg    = (int*)(p + o);      o += al256s((size_t)N * 4);
    float* stats  = (float*)(p + o);    o += 256 * 4;           // sum[128],sq[128]
    o = al256s(o);
    u16*   wpre   = (u16*)(p + o);      o += al256s(2 * 16384 * 2);  // 2 bf16 planes
    int*   bsums  = (int*)(p + o);      o += al256s(((size_t)nblk + 8) * 4);
    int*   offs   = (int*)(p + o);      o += al256s(((size_t)N + 8) * 4);
    int*   csr    = (int*)(p + o);      o += al256s((size_t)E * 4);
    float* parts  = (float*)(p + o);    o += al256s((size_t)gb * 256 * 4);
    // union region: agg (Npad*256B) overlaid with cnt/bases (NSTRIPE*N*4B);
    // cnt dies before k_aggregate writes agg.
    size_t aggBytes = (size_t)Npad * D_DIM * 2;
    size_t cntBytes = (size_t)NSTRIPE * N * 4;
    u16*   agg    = (u16*)(p + o);
    int*   cnt    = (int*)(p + o);      o += al256s(smax(aggBytes, cntBytes));
    u16*   fbf    = (u16*)d_out; // bf16 feature copy; dead before k_apply writes
    (void)ws_size; (void)n_in; (void)out_size;

    int total8 = N * D_DIM / 8;
    int zb = 1;                                    // stats zero fits one block
    int tb = gmax1((total8 + 255) / 256);
    int hblocks = NSTRIPE * P;

    GCNLayer_76647986365164_kernel<<<zb + tb + 1, 256, 0, stream>>>(
        (int*)stats, 256, (const u32*)feature, flag,
        (const float*)feature, fbf, W, wpre, total8, zb);
    k_hist<<<hblocks, 256, 0, stream>>>(dst, cnt, E, N, nper, ES, P);
    k_colscan<<<gmax1((N + 255) / 256), 256, 0, stream>>>(cnt, deg, N);
    k_scan_local<<<gmax1(nblk), 256, 0, stream>>>(deg, offs, bsums, N);
    k_scan_add<<<gmax1(nblk), 256, 0, stream>>>(offs, bsums, N, nblk);
    k_scatter<<<hblocks, 256, 0, stream>>>(src, dst, cnt, offs, csr,
                                           E, N, nper, ES, P);
    k_aggregate<<<gmax1(Npad / 16), 256, 0, stream>>>(
        feature, fbf, offs, csr, agg, flag, N, Npad);
    k_gemm<<<gmax1(gb), 512, 0, stream>>>(agg, wpre, bias, parts, flag, N);
    k_redstats<<<32, 256, 0, stream>>>(parts, stats, gb);
    k_apply<<<gmax1((total8 + 255) / 256), 256, 0, stream>>>(
        agg, feature, stats, gamma, beta, d_out, flag, total8, 1.0f / (float)N);
}

// Round 11
// 270.255 us; speedup vs baseline: 1.1822x; 1.0405x over previous
//
#include <hip/hip_runtime.h>

typedef unsigned short u16;
typedef unsigned int u32;

#define D_DIM 128
#define CHUNK 4096    // elements scanned per scan block (256 threads x 16)
#define NSTRIPE 64    // edge stripes for hist/scatter (cnt = 64*N*4B fits union)
#define LCN 12800     // LDS counters per partition block (51.2 KB)

typedef __attribute__((ext_vector_type(8))) short bf16x8;
typedef __attribute__((ext_vector_type(4))) float f32x4;

__device__ __forceinline__ float bf2f(u16 h) {
    u32 u = ((u32)h) << 16;
    return __uint_as_float(u);
}
__device__ __forceinline__ u16 f2bf(float f) {
    u32 u = __float_as_uint(f);
    u32 r = (u >> 16) & 1u;
    u += 0x7fffu + r;                 // round-to-nearest-even
    return (u16)(u >> 16);
}
__device__ __forceinline__ float lo16(u32 u) { return bf2f((u16)(u & 0xffffu)); }
__device__ __forceinline__ float hi16(u32 u) { return bf2f((u16)(u >> 16)); }

// --- K1 (fused front): zero stats + dtype detect + fp32->bf16 feature copy
//     + W prepack. Per-block SELF-detection of dtype (same 4KB of feature,
//     L2-broadcast, identical result in every block -> no cross-block order).
__global__ void GCNLayer_76647986365164_kernel(
        int* p, int nwords, const u32* w, int* flag,
        const float* __restrict__ f, u16* __restrict__ fb,
        const void* __restrict__ W, u16* __restrict__ wpre,
        int total8, int zb) {
    const int tid = threadIdx.x;
    const int b = blockIdx.x;
    if (b < zb) {                               // zero section (stats only now)
        int i = b * 256 + tid;
        if (i < nwords) p[i] = 0;
        return;
    }
    __shared__ int cnt;
    if (tid == 0) cnt = 0;
    __syncthreads();
    {
        int c = 0;
        for (int j = 0; j < 4; ++j) {
            u32 x = w[tid * 4 + j];
            u32 e = (x >> 7) & 0xFFu;
            if (e >= 100u && e <= 140u) c++;
        }
        atomicAdd(&cnt, c);
    }
    __syncthreads();
    const int bf = (cnt >= 700) ? 1 : 0;
    if (b == zb && tid == 0) flag[0] = bf;

    if (b == gridDim.x - 1) {                   // W prepack block
        #pragma unroll
        for (int i = 0; i < 8; ++i) {
            int idx = i * 256 + tid;            // 2048 fragment units
            int frag = idx >> 6, dl = idx & 63;
            int ot = frag >> 2, kt = frag & 3;
            int dg = dl >> 4, dc = dl & 15;
            int row = ot * 16 + dc, col = kt * 32 + dg * 8;
            if (bf) {
                *(uint4*)(wpre + (size_t)idx * 8) =
                    *(const uint4*)((const u16*)W + row * 128 + col);
            } else {
                const float* Wf = (const float*)W;
                float4 x = *(const float4*)(Wf + row * 128 + col);
                float4 y = *(const float4*)(Wf + row * 128 + col + 4);
                float v[8] = {x.x, x.y, x.z, x.w, y.x, y.y, y.z, y.w};
                u16 h0[8], h1[8];
                #pragma unroll
                for (int j = 0; j < 8; ++j) {
                    h0[j] = f2bf(v[j]);
                    h1[j] = f2bf(v[j] - bf2f(h0[j]));   // residual plane
                }
                uint4 p0, p1;
                p0.x = (u32)h0[0] | ((u32)h0[1] << 16);
                p0.y = (u32)h0[2] | ((u32)h0[3] << 16);
                p0.z = (u32)h0[4] | ((u32)h0[5] << 16);
                p0.w = (u32)h0[6] | ((u32)h0[7] << 16);
                p1.x = (u32)h1[0] | ((u32)h1[1] << 16);
                p1.y = (u32)h1[2] | ((u32)h1[3] << 16);
                p1.z = (u32)h1[4] | ((u32)h1[5] << 16);
                p1.w = (u32)h1[6] | ((u32)h1[7] << 16);
                *(uint4*)(wpre + (size_t)idx * 8) = p0;
                *(uint4*)(wpre + 16384 + (size_t)idx * 8) = p1;
            }
        }
        return;
    }
    if (bf) return;                  // input already bf16, no feature copy
    int i = (b - zb) * 256 + tid;    // tobf section
    if (i >= total8) return;
    float4 a = ((const float4*)f)[i * 2];
    float4 bb = ((const float4*)f)[i * 2 + 1];
    uint4 o;
    o.x = (u32)f2bf(a.x) | ((u32)f2bf(a.y) << 16);
    o.y = (u32)f2bf(a.z) | ((u32)f2bf(a.w) << 16);
    o.z = (u32)f2bf(bb.x) | ((u32)f2bf(bb.y) << 16);
    o.w = (u32)f2bf(bb.z) | ((u32)f2bf(bb.w) << 16);
    ((uint4*)fb)[i] = o;
}

// --- K2: per-stripe per-partition histogram, ZERO global atomics ------------
__global__ __launch_bounds__(256)
void k_hist(const int* __restrict__ dst, int* __restrict__ cnt,
            int E, int N, int nper, int ES, int P) {
    __shared__ int lc[LCN];
    const int tid = threadIdx.x;
    const int p = blockIdx.x % P;
    const int s = blockIdx.x / P;
    const int lo = p * nper;
    const int hi = min(lo + nper, N);
    const int cn = hi - lo;
    for (int t = tid; t < cn; t += 256) lc[t] = 0;
    __syncthreads();
    const int base = s * ES;
    const int end = min(base + ES, E);
    for (int i = base + tid * 4; i < end; i += 1024) {
        if (i + 3 < end) {
            int4 d4 = *(const int4*)(dst + i);
            if (d4.x >= lo && d4.x < hi) atomicAdd(&lc[d4.x - lo], 1);
            if (d4.y >= lo && d4.y < hi) atomicAdd(&lc[d4.y - lo], 1);
            if (d4.z >= lo && d4.z < hi) atomicAdd(&lc[d4.z - lo], 1);
            if (d4.w >= lo && d4.w < hi) atomicAdd(&lc[d4.w - lo], 1);
        } else {
            for (int k = i; k < end; ++k) {
                int d = dst[k];
                if (d >= lo && d < hi) atomicAdd(&lc[d - lo], 1);
            }
        }
    }
    __syncthreads();
    int* crow = cnt + (size_t)s * N + lo;
    for (int t = tid; t < cn; t += 256) crow[t] = lc[t];
}

// --- K2b: per-node exclusive prefix over stripes (in place) + deg -----------
__global__ void k_colscan(int* __restrict__ cnt, int* __restrict__ deg, int N) {
    int n = blockIdx.x * 256 + threadIdx.x;
    if (n >= N) return;
    int run = 0;
    #pragma unroll
    for (int s = 0; s < NSTRIPE; ++s) {
        int t = cnt[(size_t)s * N + n];
        cnt[(size_t)s * N + n] = run;          // cnt becomes `bases`
        run += t;
    }
    deg[n] = run;
}

// --- K3a: block-local exclusive scan (multi-block; LDS Hillis-Steele) -------
__global__ void k_scan_local(const int* deg, int* offs, int* bsums, int n) {
    __shared__ int tsum[256];
    const int tid = threadIdx.x;
    const int base = blockIdx.x * CHUNK + tid * 16;
    int v[16];
    int run = 0;
    for (int j = 0; j < 16; ++j) {
        int idx = base + j;
        v[j] = (idx < n) ? deg[idx] : 0;
        run += v[j];
    }
    tsum[tid] = run;
    __syncthreads();
    for (int off = 1; off < 256; off <<= 1) {      // inclusive scan of thread sums
        int val = tsum[tid];
        int add = (tid >= off) ? tsum[tid - off] : 0;
        __syncthreads();
        tsum[tid] = val + add;
        __syncthreads();
    }
    int acc = tsum[tid] - run;                     // exclusive start (local)
    for (int j = 0; j < 16; ++j) {
        int idx = base + j;
        if (idx < n) offs[idx] = acc;
        acc += v[j];
    }
    if (tid == 255) bsums[blockIdx.x] = tsum[255];
}

// --- K3b: add scanned block totals; carry via wave-parallel reduce ----------
__global__ void k_scan_add(int* offs, const int* bsums, int n, int nblk) {
    __shared__ int carry_s;
    const int tid = threadIdx.x;
    const int b = blockIdx.x;
    if (tid < 64) {
        int acc = 0;
        for (int k = tid; k < b; k += 64) acc += bsums[k];
        #pragma unroll
        for (int off = 1; off < 64; off <<= 1) acc += __shfl_xor(acc, off);
        if (tid == 0) {
            carry_s = acc;
            if (b == nblk - 1) offs[n] = acc + bsums[b];   // total == E
        }
    }
    __syncthreads();
    const int carry = carry_s;
    const int base = b * CHUNK + tid * 16;
    for (int j = 0; j < 16; ++j) {
        int idx = base + j;
        if (idx < n) offs[idx] += carry;
    }
}

// --- K4: scatter, counters PRE-INITIALIZED with absolute csr positions ------
__global__ __launch_bounds__(256)
void k_scatter(const int* __restrict__ src, const int* __restrict__ dst,
               const int* __restrict__ bases, const int* __restrict__ offs,
               int* __restrict__ csr, int E, int N, int nper, int ES, int P) {
    __shared__ int lc[LCN];
    const int tid = threadIdx.x;
    const int p = blockIdx.x % P;
    const int s = blockIdx.x / P;
    const int lo = p * nper;
    const int hi = min(lo + nper, N);
    const int cn = hi - lo;
    const int* brow = bases + (size_t)s * N;
    for (int t = tid; t < cn; t += 256)
        lc[t] = offs[lo + t] + brow[lo + t];
    __syncthreads();
    const int base = s * ES;
    const int end = min(base + ES, E);
    for (int i = base + tid * 4; i < end; i += 1024) {
        if (i + 3 < end) {
            int4 d4 = *(const int4*)(dst + i);
            int4 s4 = *(const int4*)(src + i);
            if (d4.x >= lo && d4.x < hi) csr[atomicAdd(&lc[d4.x - lo], 1)] = s4.x;
            if (d4.y >= lo && d4.y < hi) csr[atomicAdd(&lc[d4.y - lo], 1)] = s4.y;
            if (d4.z >= lo && d4.z < hi) csr[atomicAdd(&lc[d4.z - lo], 1)] = s4.z;
            if (d4.w >= lo && d4.w < hi) csr[atomicAdd(&lc[d4.w - lo], 1)] = s4.w;
        } else {
            for (int k = i; k < end; ++k) {
                int d = dst[k];
                if (d >= lo && d < hi) csr[atomicAdd(&lc[d - lo], 1)] = src[k];
            }
        }
    }
}

// --- K5+K6 FUSED: aggregate into LDS, then h = agg @ W^T + b via MFMA -------
// R11: the separate kernels cost 45us (aggregate) + ~40us (gemm, hidden under
// the cutoff since R6) with a 51.2MB agg HBM round-trip between them. Fused:
// agg rows live only in LDS; the 34KB buffer is TIME-MULTIPLEXED:
//   (1) gather 128 nodes -> sBuf[128][136] bf16 (pad 136: 2-way max on both
//       the chunk stores and the b128 A-frag reads)
//   (2) each wave pulls its A-frags (64B/lane) to registers; barrier
//   (3) sBuf overwritten with W plane (fragment order, coalesced); MFMA
//   (4) fp32 path: restage plane1 over sBuf, MFMA again (hi+lo planes)
//   (5) sBuf reused as BN-partial scratch; one coalesced parts row/block
// 34KB LDS + launch_bounds(512,8) (<=64 VGPR, R10 gemm fit exactly 64) ->
// 4 blocks/CU = 32 waves/CU for the gather phase (vs 20 in the split version).
// Numerics identical to split: agg bf16-rounded before MFMA, same sum order.
__global__ __launch_bounds__(512, 8)
void k_agg_gemm(const void* feature, const u16* __restrict__ fcopy,
                const int* __restrict__ offs, const int* __restrict__ csr,
                const u16* __restrict__ wpre, const void* __restrict__ bias,
                u16* __restrict__ hout, float* __restrict__ parts,
                const int* __restrict__ flag, int n) {
    __shared__ u16 sBuf[128 * 136];            // 34 KB, triple-purpose
    const int tid = threadIdx.x;
    const int rb = blockIdx.x * 128;
    const int bf = flag[0];
    const u16* fbp = bf ? (const u16*)feature : fcopy;
    const uint4* fq = (const uint4*)fbp;       // bf16 row = 16 uint4

    // ---- phase 1: gather-aggregate 128 nodes into sBuf -----------------
    {
        const int c = tid & 15;                // 16B chunk within row
        for (int pass = 0; pass < 4; ++pass) {
            const int nd = pass * 32 + (tid >> 4);   // 0..127
            const int node = rb + nd;
            float acc[8];
            #pragma unroll
            for (int t = 0; t < 8; ++t) acc[t] = 0.f;
            int degn = 0;
            if (node < n) {
                int s = offs[node], e = offs[node + 1];
                degn = e - s;
                for (int j = s; j < e; j += 4) {
                    int j1 = j + 1, j2 = j + 2, j3 = j + 3;
                    uint4 u0 = {0,0,0,0}, u1 = {0,0,0,0};
                    uint4 u2 = {0,0,0,0}, u3 = {0,0,0,0};
                    u0 = fq[(size_t)csr[j] * 16 + c];          // j<e by loop cond
                    if (j1 < e) u1 = fq[(size_t)csr[j1] * 16 + c];
                    if (j2 < e) u2 = fq[(size_t)csr[j2] * 16 + c];
                    if (j3 < e) u3 = fq[(size_t)csr[j3] * 16 + c];
                    #define ACC8(U) \
                        acc[0] += lo16(U.x); acc[1] += hi16(U.x); \
                        acc[2] += lo16(U.y); acc[3] += hi16(U.y); \
                        acc[4] += lo16(U.z); acc[5] += hi16(U.z); \
                        acc[6] += lo16(U.w); acc[7] += hi16(U.w);
                    ACC8(u0); ACC8(u1); ACC8(u2); ACC8(u3);
                    #undef ACC8
                }
            }
            float sc = 1.0f / (float)(degn > 1 ? degn : 1);
            uint4 o4;
            o4.x = (u32)f2bf(acc[0] * sc) | ((u32)f2bf(acc[1] * sc) << 16);
            o4.y = (u32)f2bf(acc[2] * sc) | ((u32)f2bf(acc[3] * sc) << 16);
            o4.z = (u32)f2bf(acc[4] * sc) | ((u32)f2bf(acc[5] * sc) << 16);
            o4.w = (u32)f2bf(acc[6] * sc) | ((u32)f2bf(acc[7] * sc) << 16);
            *(uint4*)(&sBuf[nd * 136 + c * 8]) = o4;
        }
    }
    __syncthreads();

    // ---- phase 2: A-fragments to registers (64B/lane) ------------------
    const int w = tid >> 6;
    const int lane = tid & 63;
    const int g = lane >> 4, cl = lane & 15;
    bf16x8 afr[4];
    #pragma unroll
    for (int kt = 0; kt < 4; ++kt)
        afr[kt] = *(const bf16x8*)(&sBuf[(w * 16 + cl) * 136 + g * 8 + kt * 32]);

    f32x4 acc[8];
    #pragma unroll
    for (int ot = 0; ot < 8; ++ot) acc[ot] = (f32x4){0.f, 0.f, 0.f, 0.f};

    // ---- phase 3/4: W plane(s) over sBuf, MFMA -------------------------
    const int npass = bf ? 1 : 2;
    for (int pass = 0; pass < npass; ++pass) {
        __syncthreads();                       // afr reads / prev MFMA done
        const u16* wsrc = wpre + (size_t)pass * 16384;
        #pragma unroll
        for (int i = 0; i < 4; ++i) {          // coalesced uint4 copy
            int idx = i * 512 + tid;
            *(uint4*)(&sBuf[idx * 8]) = *(const uint4*)(wsrc + (size_t)idx * 8);
        }
        __syncthreads();
        #pragma unroll
        for (int ot = 0; ot < 8; ++ot) {
            #pragma unroll
            for (int kt = 0; kt < 4; ++kt) {
                bf16x8 bfr = *(const bf16x8*)(&sBuf[((ot * 4 + kt) * 64 + lane) * 8]);
                acc[ot] = __builtin_amdgcn_mfma_f32_16x16x32_bf16(
                    afr[kt], bfr, acc[ot], 0, 0, 0);
            }
        }
    }

    // ---- phase 5: epilogue (bias, BN partials, packed bf16 h store) ----
    float* red = (float*)sBuf;                 // [8][256] floats = 8 KB
    __syncthreads();                           // all waves done reading sBuf

    const int rowbase = rb + w * 16 + g * 4;
    #pragma unroll
    for (int ot = 0; ot < 8; ++ot) {
        const int o = ot * 16 + cl;
        float bv = bf ? bf2f(((const u16*)bias)[o]) : ((const float*)bias)[o];
        float s = 0.f, q = 0.f;
        float hv[4];
        #pragma unroll
        for (int r = 0; r < 4; ++r) {
            float h = acc[ot][r] + bv;
            hv[r] = h;
            if (rowbase + r < n) { s += h; q += h * h; }
        }
        #pragma unroll
        for (int r = 0; r < 4; ++r) {
            float hp = __shfl_xor(hv[r], 1);       // neighbor col (o^1)
            if (!(lane & 1)) {
                u32 pk = (u32)f2bf(hv[r]) | ((u32)f2bf(hp) << 16);
                *(u32*)(hout + (size_t)(rowbase + r) * D_DIM + o) = pk;
            }
        }
        s += __shfl_xor(s, 16); s += __shfl_xor(s, 32);
        q += __shfl_xor(q, 16); q += __shfl_xor(q, 32);
        if (g == 0) { red[w * 256 + o] = s; red[w * 256 + 128 + o] = q; }
    }
    __syncthreads();
    if (tid < 256) {                            // cross-wave reduce, one row/block
        float a = 0.f;
        #pragma unroll
        for (int ww = 0; ww < 8; ++ww) a += red[ww * 256 + tid];
        parts[(size_t)blockIdx.x * 256 + tid] = a;
    }
}

// --- K6b: reduce per-block BN partials into stats ---------------------------
__global__ void k_redstats(const float* __restrict__ partials,
                           float* __restrict__ stats, int nb) {
    const int tid = threadIdx.x;
    float a0 = 0.f, a1 = 0.f, a2 = 0.f, a3 = 0.f;
    float a4 = 0.f, a5 = 0.f, a6 = 0.f, a7 = 0.f;
    for (int r0 = blockIdx.x * 8; r0 < nb; r0 += gridDim.x * 8) {
        if (r0 + 0 < nb) a0 += partials[(size_t)(r0 + 0) * 256 + tid];
        if (r0 + 1 < nb) a1 += partials[(size_t)(r0 + 1) * 256 + tid];
        if (r0 + 2 < nb) a2 += partials[(size_t)(r0 + 2) * 256 + tid];
        if (r0 + 3 < nb) a3 += partials[(size_t)(r0 + 3) * 256 + tid];
        if (r0 + 4 < nb) a4 += partials[(size_t)(r0 + 4) * 256 + tid];
        if (r0 + 5 < nb) a5 += partials[(size_t)(r0 + 5) * 256 + tid];
        if (r0 + 6 < nb) a6 += partials[(size_t)(r0 + 6) * 256 + tid];
        if (r0 + 7 < nb) a7 += partials[(size_t)(r0 + 7) * 256 + tid];
    }
    float s = ((a0 + a1) + (a2 + a3)) + ((a4 + a5) + (a6 + a7));
    atomicAdd(&stats[tid], s);
}

// --- K8: out = feature + relu(h*scale + shift); BN finalize folded in -------
__global__ void k_apply(const u16* h, const void* feature, const float* stats,
                        const void* gamma, const void* beta, void* outp,
                        const int* flag, int total8, float invn) {
    __shared__ float ssc[128], ssh[128];
    int tid = threadIdx.x;
    int bf = flag[0];
    if (tid < 128) {
        float mean = stats[tid] * invn;
        float var = stats[128 + tid] * invn - mean * mean;
        var = fmaxf(var, 0.f);
        float inv = rsqrtf(var + 1e-5f);
        float g = bf ? bf2f(((const u16*)gamma)[tid]) : ((const float*)gamma)[tid];
        float bb = bf ? bf2f(((const u16*)beta)[tid]) : ((const float*)beta)[tid];
        float sc = inv * g;
        ssc[tid] = sc;
        ssh[tid] = bb - mean * sc;
    }
    __syncthreads();
    int i = blockIdx.x * 256 + tid;
    if (i >= total8) return;
    size_t base = (size_t)i * 8;
    int c0 = (int)(base & (D_DIM - 1));
    uint4 h4 = ((const uint4*)h)[i];
    u32 hw[4] = {h4.x, h4.y, h4.z, h4.w};
    float hv[8];
    for (int j = 0; j < 4; ++j) { hv[2*j] = lo16(hw[j]); hv[2*j+1] = hi16(hw[j]); }
    float fv[8];
    if (bf) {
        uint4 f4 = ((const uint4*)feature)[i];
        u32 fw[4] = {f4.x, f4.y, f4.z, f4.w};
        for (int j = 0; j < 4; ++j) { fv[2*j] = lo16(fw[j]); fv[2*j+1] = hi16(fw[j]); }
    } else {
        float4 fa = ((const float4*)feature)[i * 2];
        float4 fb = ((const float4*)feature)[i * 2 + 1];
        fv[0]=fa.x; fv[1]=fa.y; fv[2]=fa.z; fv[3]=fa.w;
        fv[4]=fb.x; fv[5]=fb.y; fv[6]=fb.z; fv[7]=fb.w;
    }
    float ov[8];
    for (int j = 0; j < 8; ++j)
        ov[j] = fmaxf(hv[j] * ssc[c0 + j] + ssh[c0 + j], 0.f) + fv[j];
    if (bf) {
        uint4 o4;
        u32 ow[4];
        for (int j = 0; j < 4; ++j)
            ow[j] = (u32)f2bf(ov[2*j]) | ((u32)f2bf(ov[2*j+1]) << 16);
        o4.x = ow[0]; o4.y = ow[1]; o4.z = ow[2]; o4.w = ow[3];
        ((uint4*)outp)[i] = o4;
    } else {
        float4 oa, ob;
        oa.x=ov[0]; oa.y=ov[1]; oa.z=ov[2]; oa.w=ov[3];
        ob.x=ov[4]; ob.y=ov[5]; ob.z=ov[6]; ob.w=ov[7];
        ((float4*)outp)[i * 2] = oa;
        ((float4*)outp)[i * 2 + 1] = ob;
    }
}

static inline size_t al256s(size_t x) { return (x + 255) & ~(size_t)255; }
static inline int gmax1(int x) { return x > 0 ? x : 1; }
static inline size_t smax(size_t a, size_t b) { return a > b ? a : b; }

extern "C" void kernel_launch(void* const* d_in, const int* in_sizes, int n_in,
                              void* d_out, int out_size, void* d_ws, size_t ws_size,
                              hipStream_t stream) {
    const void* feature = d_in[0];
    const int*  src     = (const int*)d_in[1];
    const int*  dst     = (const int*)d_in[2];
    const void* W       = d_in[3];
    const void* bias    = d_in[4];
    const void* gamma   = d_in[5];
    const void* beta    = d_in[6];

    const int N = in_sizes[0] / D_DIM;
    const int E = in_sizes[1];
    const int Npad = (N + 127) & ~127;             // 128-row agg_gemm blocks
    const int nblk = (N + CHUNK - 1) / CHUNK;      // scan blocks
    const int gb   = Npad / 128;                   // agg_gemm blocks == partial rows

    // hist/scatter geometry: P partitions sized to fit LDS counters
    int P = (N + LCN - 1) / LCN;  if (P < 8) P = 8;
    const int nper = (N + P - 1) / P;
    const int ES = (((E + NSTRIPE - 1) / NSTRIPE) + 3) & ~3;   // 16B-aligned stripes

    char* p = (char*)d_ws;
    size_t o = 0;
    int*   flag   = (int*)(p + o);      o += 256;
    int*   deg    = (int*)(p + o);      o += al256s((size_t)N * 4);
    float* stats  = (float*)(p + o);    o += 256 * 4;           // sum[128],sq[128]
    o = al256s(o);
    u16*   wpre   = (u16*)(p + o);      o += al256s(2 * 16384 * 2);  // 2 bf16 planes
    int*   bsums  = (int*)(p + o);      o += al256s(((size_t)nblk + 8) * 4);
    int*   offs   = (int*)(p + o);      o += al256s(((size_t)N + 8) * 4);
    int*   csr    = (int*)(p + o);      o += al256s((size_t)E * 4);
    float* parts  = (float*)(p + o);    o += al256s((size_t)gb * 256 * 4);
    // union region: h (Npad*256B) overlaid with cnt/bases (NSTRIPE*N*4B);
    // cnt dies at end of k_scatter, before k_agg_gemm writes h.
    size_t hBytes   = (size_t)Npad * D_DIM * 2;
    size_t cntBytes = (size_t)NSTRIPE * N * 4;
    u16*   hbuf   = (u16*)(p + o);
    int*   cnt    = (int*)(p + o);      o += al256s(smax(hBytes, cntBytes));
    u16*   fbf    = (u16*)d_out; // bf16 feature copy; dead before k_apply writes
    (void)ws_size; (void)n_in; (void)out_size;

    int total8 = N * D_DIM / 8;
    int zb = 1;                                    // stats zero fits one block
    int tb = gmax1((total8 + 255) / 256);
    int hblocks = NSTRIPE * P;

    GCNLayer_76647986365164_kernel<<<zb + tb + 1, 256, 0, stream>>>(
        (int*)stats, 256, (const u32*)feature, flag,
        (const float*)feature, fbf, W, wpre, total8, zb);
    k_hist<<<hblocks, 256, 0, stream>>>(dst, cnt, E, N, nper, ES, P);
    k_colscan<<<gmax1((N + 255) / 256), 256, 0, stream>>>(cnt, deg, N);
    k_scan_local<<<gmax1(nblk), 256, 0, stream>>>(deg, offs, bsums, N);
    k_scan_add<<<gmax1(nblk), 256, 0, stream>>>(offs, bsums, N, nblk);
    k_scatter<<<hblocks, 256, 0, stream>>>(src, dst, cnt, offs, csr,
                                           E, N, nper, ES, P);
    k_agg_gemm<<<gmax1(gb), 512, 0, stream>>>(
        feature, fbf, offs, csr, wpre, bias, hbuf, parts, flag, N);
    k_redstats<<<32, 256, 0, stream>>>(parts, stats, gb);
    k_apply<<<gmax1((total8 + 255) / 256), 256, 0, stream>>>(
        hbuf, feature, stats, gamma, beta, d_out, flag, total8, 1.0f / (float)N);
}